// Round 3
// baseline (312.824 us; speedup 1.0000x reference)
//
#include <hip/hip_runtime.h>

// B=4, N=8, C=256, H=64, W=64, D=512 (single query per batch).
// Algebraic collapse (R1): c read exactly once; K and V never formed.
//   gqk[b,c]  = g[c] * D^-0.5 * (Wkv_upper^T (Wq q_b))[c]
//   dots[n]   = inv_rms[n] * <cp[n,:], gqk[b,:]>   (per pixel)
//   t[c]      = sum_n softmax_n * inv_rms[n] * cp[n,c]
//   out       = Wovg @ t + bo,  Wovg = Wo @ Wkv_lower * diag(g)  (bf16 MFMA)
// R2: 512 half-row blocks, 1 barrier/token, A-fragment-linear Wovg.
// R3: pre tiled 4 i-rows/block (L2 128->32 MB); attn 512-thr blocks
//     (16-ch groups, ~72 VGPR) -> 16 waves/CU for latency hiding.

typedef __attribute__((ext_vector_type(8))) short short8;
typedef __attribute__((ext_vector_type(4))) float floatx4;

static __device__ __forceinline__ short f2bf(float f) {
  unsigned u = __float_as_uint(f);
  u += 0x7fffu + ((u >> 16) & 1u);   // round-to-nearest-even
  return (short)(u >> 16);
}

// ws: [0,131072) WovgB bf16, A-fragment-linear: element (i,c) at short index
//     ((((i>>4)*8 + (c>>5))*4 + ((c>>3)&3))*16 + (i&15))*8 + (c&7)
//     [131072,135168) gqk f32 [4][256]
__global__ __launch_bounds__(256) void pre_kernel(
    const float* __restrict__ q, const float* __restrict__ g,
    const float* __restrict__ Wq, const float* __restrict__ Wkv,
    const float* __restrict__ Wo, unsigned char* __restrict__ ws) {
  short* WovgB = (short*)ws;
  float* gqk = (float*)(ws + 131072);
  const int blk = blockIdx.x, tid = threadIdx.x;
  if (blk < 64) {
    // 4 i-rows per block: one pass over Wkv lower half serves 4 rows.
    const int c = tid, i0 = blk * 4;
    float s0 = 0.f, s1 = 0.f, s2 = 0.f, s3 = 0.f;
    #pragma unroll 8
    for (int d = 0; d < 512; ++d) {
      const float wv = Wkv[(512 + d) * 256 + c];   // coalesced; L2-resident
      s0 = fmaf(Wo[(i0 + 0) * 512 + d], wv, s0);   // uniform -> scalar loads
      s1 = fmaf(Wo[(i0 + 1) * 512 + d], wv, s1);
      s2 = fmaf(Wo[(i0 + 2) * 512 + d], wv, s2);
      s3 = fmaf(Wo[(i0 + 3) * 512 + d], wv, s3);
    }
    const float gc = g[c];
    const float sv[4] = {s0, s1, s2, s3};
    const int sg = c >> 5, q2 = (c >> 3) & 3, jj = c & 7;
    #pragma unroll
    for (int r = 0; r < 4; ++r) {
      const int i = i0 + r;
      const int it = i >> 4, m = i & 15;
      WovgB[((((it * 8 + sg) * 4 + q2) * 16) + m) * 8 + jj] = f2bf(sv[r] * gc);
    }
  } else {
    const int b = blk - 64;
    __shared__ float qps[512];
    for (int d = tid; d < 512; d += 256) {
      float s = 0.f;
      #pragma unroll 16
      for (int cc = 0; cc < 256; ++cc)
        s = fmaf(Wq[d * 256 + cc], q[b * 256 + cc], s);
      qps[d] = s;
    }
    __syncthreads();
    const int c = tid;
    float s = 0.f;
    #pragma unroll 16
    for (int d = 0; d < 512; ++d)
      s = fmaf(Wkv[d * 256 + c], qps[d], s);
    gqk[b * 256 + c] = s * g[c] * 0.044194173824159216f;  // 512^-0.5
  }
}

// Block = (b, h, half-row): 32 px, 512 threads = 8 waves. Lane = cgh*32+px;
// channel group cg = w*2+cgh owns 16 channels [cg*16, cg*16+16).
__global__ __launch_bounds__(512, 4) void attn_kernel(
    const float* __restrict__ cin, const float* __restrict__ bo,
    const unsigned char* __restrict__ ws, float* __restrict__ out) {
  const short8* Av = (const short8*)ws;
  const float* gqk = (const float*)(ws + 131072);
  const int blk = blockIdx.x;                 // 512 blocks
  const int b = blk >> 7, h = (blk >> 1) & 63, hf = blk & 1;
  const int tid = threadIdx.x;
  const int lane = tid & 63, w = tid >> 6;    // w: 0..7
  const int px = lane & 31, cgh = lane >> 5;
  const int cg = w * 2 + cgh;                 // 0..15

  __shared__ short tB[8][2][64][8];           // 16 KB, B-fragment-linear
  __shared__ float redS[2][8][32], redD[2][8][32];  // 4 KB, double-buffered

  float rg[16];
  #pragma unroll
  for (int j = 0; j < 16; ++j) rg[j] = gqk[b * 256 + cg * 16 + j];

  float t_reg[16];
  #pragma unroll
  for (int j = 0; j < 16; ++j) t_reg[j] = 0.f;
  float mM = -1e30f, zZ = 0.f;

  const float* cb = cin + ((size_t)(b * 8) * 256 + cg * 16) * 4096
                        + h * 64 + hf * 32 + px;
  for (int n = 0; n < 8; ++n) {
    const float* cp = cb + (size_t)n * 256 * 4096;
    float vals[16];
    #pragma unroll
    for (int j = 0; j < 16; ++j) vals[j] = cp[(size_t)j * 4096];
    float ssq = 0.f, dt = 0.f;
    #pragma unroll
    for (int j = 0; j < 16; ++j) {
      ssq = fmaf(vals[j], vals[j], ssq);
      dt = fmaf(vals[j], rg[j], dt);
    }
    ssq += __shfl_xor(ssq, 32);               // combine wave's 2 cg halves
    dt  += __shfl_xor(dt, 32);
    if (cgh == 0) { redS[n & 1][w][px] = ssq; redD[n & 1][w][px] = dt; }
    __syncthreads();                          // the only barrier per token
    float S = 0.f, Dt = 0.f;
    #pragma unroll
    for (int ww = 0; ww < 8; ++ww) { S += redS[n & 1][ww][px]; Dt += redD[n & 1][ww][px]; }
    const float invr = rsqrtf(S * (1.f / 256.f) + 1e-6f);
    const float d = Dt * invr;
    const float mn = fmaxf(mM, d);
    const float al = __expf(mM - mn);         // 0 on first token
    const float e = __expf(d - mn);
    zZ = zZ * al + e;
    mM = mn;
    const float wn = e * invr;
    #pragma unroll
    for (int j = 0; j < 16; ++j) t_reg[j] = fmaf(wn, vals[j], t_reg[j] * al);
  }

  // write normalized t (bf16) in B-fragment order:
  // reader lane L=(q*16+mm) of (s,nt) wants ch=s*32+q*8+jj, px=nt*16+mm.
  // writer ch = cg*16 + h2*8 + jj  ->  s=cg>>1, q=(cg&1)*2+h2.
  {
    const float invZ = 1.f / zZ;
    const int nt = px >> 4, mm = px & 15;
    const int s = cg >> 1;
    #pragma unroll
    for (int h2 = 0; h2 < 2; ++h2) {
      const int q = (cg & 1) * 2 + h2;
      short8 pk;
      #pragma unroll
      for (int jj = 0; jj < 8; ++jj) pk[jj] = f2bf(t_reg[h2 * 8 + jj] * invZ);
      *(short8*)(&tB[s][nt][q * 16 + mm][0]) = pk;
    }
  }
  __syncthreads();

  // phase 3: out[256 i][32 px] = Wovg(bf16) @ t(bf16); wave w -> 32 i-rows
  const int q = lane >> 4, m = lane & 15;
  const short8* Bv = (const short8*)tB;
  floatx4 acc[2][2];
  #pragma unroll
  for (int mt = 0; mt < 2; ++mt)
    #pragma unroll
    for (int nt = 0; nt < 2; ++nt) acc[mt][nt] = (floatx4){0.f, 0.f, 0.f, 0.f};
  #pragma unroll
  for (int s = 0; s < 8; ++s) {
    short8 a[2];
    #pragma unroll
    for (int mt = 0; mt < 2; ++mt)            // coalesced: 16 B/lane, 1 KB/wave
      a[mt] = Av[(((w * 2 + mt) * 8 + s) * 4 + q) * 16 + m];
    #pragma unroll
    for (int nt = 0; nt < 2; ++nt) {
      const short8 bf = Bv[(s * 2 + nt) * 64 + lane];
      #pragma unroll
      for (int mt = 0; mt < 2; ++mt)
        acc[mt][nt] = __builtin_amdgcn_mfma_f32_16x16x32_bf16(a[mt], bf, acc[mt][nt], 0, 0, 0);
    }
  }
  // epilogue: D layout col=lane&15(px), row=q*4+r(i)
  float* ob = out + (size_t)b * 256 * 4096 + h * 64 + hf * 32;
  #pragma unroll
  for (int mt = 0; mt < 2; ++mt) {
    float bov[4];
    #pragma unroll
    for (int r = 0; r < 4; ++r) bov[r] = bo[w * 32 + mt * 16 + q * 4 + r];
    #pragma unroll
    for (int nt = 0; nt < 2; ++nt)
      #pragma unroll
      for (int r = 0; r < 4; ++r) {
        const int i = w * 32 + mt * 16 + q * 4 + r;
        ob[(size_t)i * 4096 + nt * 16 + m] = acc[mt][nt][r] + bov[r];
      }
  }
}

extern "C" void kernel_launch(void* const* d_in, const int* in_sizes, int n_in,
                              void* d_out, int out_size, void* d_ws, size_t ws_size,
                              hipStream_t stream) {
  const float* q   = (const float*)d_in[0];
  const float* c   = (const float*)d_in[1];
  const float* g   = (const float*)d_in[2];
  const float* Wq  = (const float*)d_in[3];
  const float* Wkv = (const float*)d_in[4];
  const float* Wo  = (const float*)d_in[5];
  const float* bo  = (const float*)d_in[6];
  float* out = (float*)d_out;
  unsigned char* ws = (unsigned char*)d_ws;   // needs 135168 bytes
  pre_kernel<<<68, 256, 0, stream>>>(q, g, Wq, Wkv, Wo, ws);
  attn_kernel<<<512, 512, 0, stream>>>(c, bo, ws, out);
}

// Round 4
// 255.067 us; speedup vs baseline: 1.2264x; 1.2264x over previous
//
#include <hip/hip_runtime.h>

// B=4, N=8, C=256, H=64, W=64, D=512 (single query per batch).
// Algebraic collapse (R1): c read exactly once; K and V never formed.
//   gqk[b,c]  = g[c] * D^-0.5 * (Wkv_upper^T (Wq q_b))[c]
//   dots[n]   = inv_rms[n] * <cp[n,:], gqk[b,:]>   (per pixel)
//   t[c]      = sum_n softmax_n * inv_rms[n] * cp[n,c]
//   out       = Wovg @ t + bo,  Wovg = Wo @ Wkv_lower * diag(g)  (bf16 MFMA)
// R2: 512 half-row blocks, 1 barrier/token, A-fragment-linear Wovg.
// R3: pre tiled 4 i-rows/block; 512-thr attn. REGRESSED: launch_bounds(512,4)
//     forced VGPR=64 -> scratch spills -> 141 MB phantom HBM writes.
// R4: launch_bounds(512) (no VGPR cap, no spill) + software-pipelined c loads
//     (token n+1 issued before token n's barrier).

typedef __attribute__((ext_vector_type(8))) short short8;
typedef __attribute__((ext_vector_type(4))) float floatx4;

static __device__ __forceinline__ short f2bf(float f) {
  unsigned u = __float_as_uint(f);
  u += 0x7fffu + ((u >> 16) & 1u);   // round-to-nearest-even
  return (short)(u >> 16);
}

// ws: [0,131072) WovgB bf16, A-fragment-linear: element (i,c) at short index
//     ((((i>>4)*8 + (c>>5))*4 + ((c>>3)&3))*16 + (i&15))*8 + (c&7)
//     [131072,135168) gqk f32 [4][256]
__global__ __launch_bounds__(256) void pre_kernel(
    const float* __restrict__ q, const float* __restrict__ g,
    const float* __restrict__ Wq, const float* __restrict__ Wkv,
    const float* __restrict__ Wo, unsigned char* __restrict__ ws) {
  short* WovgB = (short*)ws;
  float* gqk = (float*)(ws + 131072);
  const int blk = blockIdx.x, tid = threadIdx.x;
  if (blk < 64) {
    // 4 i-rows per block: one pass over Wkv lower half serves 4 rows.
    const int c = tid, i0 = blk * 4;
    float s0 = 0.f, s1 = 0.f, s2 = 0.f, s3 = 0.f;
    #pragma unroll 8
    for (int d = 0; d < 512; ++d) {
      const float wv = Wkv[(512 + d) * 256 + c];   // coalesced; L2-resident
      s0 = fmaf(Wo[(i0 + 0) * 512 + d], wv, s0);   // uniform -> scalar loads
      s1 = fmaf(Wo[(i0 + 1) * 512 + d], wv, s1);
      s2 = fmaf(Wo[(i0 + 2) * 512 + d], wv, s2);
      s3 = fmaf(Wo[(i0 + 3) * 512 + d], wv, s3);
    }
    const float gc = g[c];
    const float sv[4] = {s0, s1, s2, s3};
    const int sg = c >> 5, q2 = (c >> 3) & 3, jj = c & 7;
    #pragma unroll
    for (int r = 0; r < 4; ++r) {
      const int i = i0 + r;
      const int it = i >> 4, m = i & 15;
      WovgB[((((it * 8 + sg) * 4 + q2) * 16) + m) * 8 + jj] = f2bf(sv[r] * gc);
    }
  } else {
    const int b = blk - 64;
    __shared__ float qps[512];
    for (int d = tid; d < 512; d += 256) {
      float s = 0.f;
      #pragma unroll 16
      for (int cc = 0; cc < 256; ++cc)
        s = fmaf(Wq[d * 256 + cc], q[b * 256 + cc], s);
      qps[d] = s;
    }
    __syncthreads();
    const int c = tid;
    float s = 0.f;
    #pragma unroll 16
    for (int d = 0; d < 512; ++d)
      s = fmaf(Wkv[d * 256 + c], qps[d], s);
    gqk[b * 256 + c] = s * g[c] * 0.044194173824159216f;  // 512^-0.5
  }
}

// Block = (b, h, half-row): 32 px, 512 threads = 8 waves. Lane = cgh*32+px;
// channel group cg = w*2+cgh owns 16 channels [cg*16, cg*16+16).
__global__ __launch_bounds__(512) void attn_kernel(
    const float* __restrict__ cin, const float* __restrict__ bo,
    const unsigned char* __restrict__ ws, float* __restrict__ out) {
  const short8* Av = (const short8*)ws;
  const float* gqk = (const float*)(ws + 131072);
  const int blk = blockIdx.x;                 // 512 blocks
  const int b = blk >> 7, h = (blk >> 1) & 63, hf = blk & 1;
  const int tid = threadIdx.x;
  const int lane = tid & 63, w = tid >> 6;    // w: 0..7
  const int px = lane & 31, cgh = lane >> 5;
  const int cg = w * 2 + cgh;                 // 0..15

  __shared__ short tB[8][2][64][8];           // 16 KB, B-fragment-linear
  __shared__ float redS[2][8][32], redD[2][8][32];  // 4 KB, double-buffered

  float rg[16];
  #pragma unroll
  for (int j = 0; j < 16; ++j) rg[j] = gqk[b * 256 + cg * 16 + j];

  float t_reg[16];
  #pragma unroll
  for (int j = 0; j < 16; ++j) t_reg[j] = 0.f;
  float mM = -1e30f, zZ = 0.f;

  const float* cb = cin + ((size_t)(b * 8) * 256 + cg * 16) * 4096
                        + h * 64 + hf * 32 + px;
  float vcur[16], vnxt[16];
  #pragma unroll
  for (int j = 0; j < 16; ++j) vcur[j] = cb[(size_t)j * 4096];  // token 0

  #pragma unroll
  for (int n = 0; n < 8; ++n) {
    float ssq = 0.f, dt = 0.f;
    #pragma unroll
    for (int j = 0; j < 16; ++j) {
      ssq = fmaf(vcur[j], vcur[j], ssq);
      dt = fmaf(vcur[j], rg[j], dt);
    }
    ssq += __shfl_xor(ssq, 32);               // combine wave's 2 cg halves
    dt  += __shfl_xor(dt, 32);
    if (cgh == 0) { redS[n & 1][w][px] = ssq; redD[n & 1][w][px] = dt; }
    if (n < 7) {                              // prefetch token n+1 BEFORE the
      const float* cp = cb + (size_t)(n + 1) * 1048576;  // barrier: HBM latency
      #pragma unroll                          // overlaps barrier + reduction
      for (int j = 0; j < 16; ++j) vnxt[j] = cp[(size_t)j * 4096];
    }
    __syncthreads();                          // the only barrier per token
    float S = 0.f, Dt = 0.f;
    #pragma unroll
    for (int ww = 0; ww < 8; ++ww) { S += redS[n & 1][ww][px]; Dt += redD[n & 1][ww][px]; }
    const float invr = rsqrtf(S * (1.f / 256.f) + 1e-6f);
    const float d = Dt * invr;
    const float mn = fmaxf(mM, d);
    const float al = __expf(mM - mn);         // 0 on first token
    const float e = __expf(d - mn);
    zZ = zZ * al + e;
    mM = mn;
    const float wn = e * invr;
    #pragma unroll
    for (int j = 0; j < 16; ++j) t_reg[j] = fmaf(wn, vcur[j], t_reg[j] * al);
    #pragma unroll
    for (int j = 0; j < 16; ++j) vcur[j] = vnxt[j];
  }

  // write normalized t (bf16) in B-fragment order:
  // reader lane L=(q*16+mm) of (s,nt) wants ch=s*32+q*8+jj, px=nt*16+mm.
  // writer ch = cg*16 + h2*8 + jj  ->  s=cg>>1, q=(cg&1)*2+h2.
  {
    const float invZ = 1.f / zZ;
    const int nt = px >> 4, mm = px & 15;
    const int s = cg >> 1;
    #pragma unroll
    for (int h2 = 0; h2 < 2; ++h2) {
      const int q = (cg & 1) * 2 + h2;
      short8 pk;
      #pragma unroll
      for (int jj = 0; jj < 8; ++jj) pk[jj] = f2bf(t_reg[h2 * 8 + jj] * invZ);
      *(short8*)(&tB[s][nt][q * 16 + mm][0]) = pk;
    }
  }
  __syncthreads();

  // phase 3: out[256 i][32 px] = Wovg(bf16) @ t(bf16); wave w -> 32 i-rows
  const int q = lane >> 4, m = lane & 15;
  const short8* Bv = (const short8*)tB;
  floatx4 acc[2][2];
  #pragma unroll
  for (int mt = 0; mt < 2; ++mt)
    #pragma unroll
    for (int nt = 0; nt < 2; ++nt) acc[mt][nt] = (floatx4){0.f, 0.f, 0.f, 0.f};
  #pragma unroll
  for (int s = 0; s < 8; ++s) {
    short8 a[2];
    #pragma unroll
    for (int mt = 0; mt < 2; ++mt)            // coalesced: 16 B/lane, 1 KB/wave
      a[mt] = Av[(((w * 2 + mt) * 8 + s) * 4 + q) * 16 + m];
    #pragma unroll
    for (int nt = 0; nt < 2; ++nt) {
      const short8 bf = Bv[(s * 2 + nt) * 64 + lane];
      #pragma unroll
      for (int mt = 0; mt < 2; ++mt)
        acc[mt][nt] = __builtin_amdgcn_mfma_f32_16x16x32_bf16(a[mt], bf, acc[mt][nt], 0, 0, 0);
    }
  }
  // epilogue: D layout col=lane&15(px), row=q*4+r(i)
  float* ob = out + (size_t)b * 256 * 4096 + h * 64 + hf * 32;
  #pragma unroll
  for (int mt = 0; mt < 2; ++mt) {
    float bov[4];
    #pragma unroll
    for (int r = 0; r < 4; ++r) bov[r] = bo[w * 32 + mt * 16 + q * 4 + r];
    #pragma unroll
    for (int nt = 0; nt < 2; ++nt)
      #pragma unroll
      for (int r = 0; r < 4; ++r) {
        const int i = w * 32 + mt * 16 + q * 4 + r;
        ob[(size_t)i * 4096 + nt * 16 + m] = acc[mt][nt][r] + bov[r];
      }
  }
}

extern "C" void kernel_launch(void* const* d_in, const int* in_sizes, int n_in,
                              void* d_out, int out_size, void* d_ws, size_t ws_size,
                              hipStream_t stream) {
  const float* q   = (const float*)d_in[0];
  const float* c   = (const float*)d_in[1];
  const float* g   = (const float*)d_in[2];
  const float* Wq  = (const float*)d_in[3];
  const float* Wkv = (const float*)d_in[4];
  const float* Wo  = (const float*)d_in[5];
  const float* bo  = (const float*)d_in[6];
  float* out = (float*)d_out;
  unsigned char* ws = (unsigned char*)d_ws;   // needs 135168 bytes
  pre_kernel<<<68, 256, 0, stream>>>(q, g, Wq, Wkv, Wo, ws);
  attn_kernel<<<512, 512, 0, stream>>>(c, bo, ws, out);
}